// Round 1
// baseline (1536.303 us; speedup 1.0000x reference)
//
#include <hip/hip_runtime.h>

#define T_DIM 4096
#define C_DIM 1024
#define H_DIM 64
#define B_DIM 4

// ---------------------------------------------------------------------------
// QKV projection: out_m = x @ W_m + b_m   (M=16384, K=1024, N=64, m in {q,k,v})
// grid (1024, 3), block 256. Thread = (4 rows, 1 col). Wave-uniform x loads
// (broadcast), coalesced W column loads (64 lanes * 4B = 256B).
// ---------------------------------------------------------------------------
__global__ __launch_bounds__(256) void qkv_proj(
    const float* __restrict__ x,
    const float* __restrict__ Wq, const float* __restrict__ bq,
    const float* __restrict__ Wk, const float* __restrict__ bk,
    const float* __restrict__ Wv, const float* __restrict__ bv,
    float* __restrict__ qo, float* __restrict__ ko, float* __restrict__ vo)
{
    const int m = blockIdx.y;
    const float* __restrict__ W    = (m == 0) ? Wq : (m == 1) ? Wk : Wv;
    const float* __restrict__ bias = (m == 0) ? bq : (m == 1) ? bk : bv;
    float* __restrict__ outp       = (m == 0) ? qo : (m == 1) ? ko : vo;

    const int h  = threadIdx.x & 63;   // output column
    const int rg = threadIdx.x >> 6;   // row group within block (0..3)
    const long r0 = (long)blockIdx.x * 16 + rg * 4;  // first of 4 rows
    const float* __restrict__ xr = x + r0 * C_DIM;

    float a0 = 0.f, a1 = 0.f, a2 = 0.f, a3 = 0.f;
#pragma unroll 2
    for (int c = 0; c < C_DIM; c += 4) {
        const float4 x0 = *(const float4*)(xr + c);
        const float4 x1 = *(const float4*)(xr + C_DIM + c);
        const float4 x2 = *(const float4*)(xr + 2 * C_DIM + c);
        const float4 x3 = *(const float4*)(xr + 3 * C_DIM + c);
        const float w0 = W[(c + 0) * H_DIM + h];
        const float w1 = W[(c + 1) * H_DIM + h];
        const float w2 = W[(c + 2) * H_DIM + h];
        const float w3 = W[(c + 3) * H_DIM + h];
        a0 += x0.x * w0 + x0.y * w1 + x0.z * w2 + x0.w * w3;
        a1 += x1.x * w0 + x1.y * w1 + x1.z * w2 + x1.w * w3;
        a2 += x2.x * w0 + x2.y * w1 + x2.z * w2 + x2.w * w3;
        a3 += x3.x * w0 + x3.y * w1 + x3.z * w2 + x3.w * w3;
    }
    const float bb = bias[h];
    outp[(r0 + 0) * H_DIM + h] = a0 + bb;
    outp[(r0 + 1) * H_DIM + h] = a1 + bb;
    outp[(r0 + 2) * H_DIM + h] = a2 + bb;
    outp[(r0 + 3) * H_DIM + h] = a3 + bb;
}

// ---------------------------------------------------------------------------
// Causal attention, flash-style without max subtraction (|s*scale| < ~1, safe).
// grid (64, 4) = (q-tile, batch), block 256 = 4 waves.
// Each thread owns one q row (lane = row-in-tile); the 4 waves split the kv
// range [0, t0+64) into 4 contiguous chunks; partials (acc[64], l) combined
// through LDS; coalesced float4 output writes.
// ---------------------------------------------------------------------------
__global__ __launch_bounds__(256) void attn_fwd(
    const float* __restrict__ q, const float* __restrict__ k,
    const float* __restrict__ v, float* __restrict__ out)
{
    __shared__ __align__(16) float part[4][64][68];  // 64 acc + 1 l + pad

    const int b    = blockIdx.y;
    const int t0   = blockIdx.x * 64;
    const int w    = threadIdx.x >> 6;
    const int lane = threadIdx.x & 63;
    const int r    = t0 + lane;  // this thread's q row (within batch)

    const float* __restrict__ qrow = q + ((size_t)b * T_DIM + r) * H_DIM;
    float qr[64];
#pragma unroll
    for (int d4 = 0; d4 < 16; ++d4) {
        const float4 t = *(const float4*)(qrow + 4 * d4);
        qr[4 * d4 + 0] = t.x; qr[4 * d4 + 1] = t.y;
        qr[4 * d4 + 2] = t.z; qr[4 * d4 + 3] = t.w;
    }

    float acc[64];
#pragma unroll
    for (int d = 0; d < 64; ++d) acc[d] = 0.f;
    float l = 0.f;

    const int kv_len = t0 + 64;      // multiple of 64
    const int chunk  = kv_len >> 2;  // per-wave kv chunk
    const int j0 = w * chunk;
    const int j1 = j0 + chunk;
    const float* __restrict__ kb = k + (size_t)b * T_DIM * H_DIM;
    const float* __restrict__ vb = v + (size_t)b * T_DIM * H_DIM;

    for (int j = j0; j < j1; ++j) {
        const float* __restrict__ krow = kb + (size_t)j * H_DIM;
        float s = 0.f;
#pragma unroll
        for (int d4 = 0; d4 < 16; ++d4) {
            const float4 kk = *(const float4*)(krow + 4 * d4);
            s += qr[4 * d4 + 0] * kk.x + qr[4 * d4 + 1] * kk.y +
                 qr[4 * d4 + 2] * kk.z + qr[4 * d4 + 3] * kk.w;
        }
        const float p = (j <= r) ? __expf(s * 0.03125f) : 0.f;
        l += p;
        const float* __restrict__ vrow = vb + (size_t)j * H_DIM;
#pragma unroll
        for (int d4 = 0; d4 < 16; ++d4) {
            const float4 vv = *(const float4*)(vrow + 4 * d4);
            acc[4 * d4 + 0] += p * vv.x; acc[4 * d4 + 1] += p * vv.y;
            acc[4 * d4 + 2] += p * vv.z; acc[4 * d4 + 3] += p * vv.w;
        }
    }

    // stage partials
#pragma unroll
    for (int d4 = 0; d4 < 16; ++d4) {
        const float4 t = make_float4(acc[4 * d4 + 0], acc[4 * d4 + 1],
                                     acc[4 * d4 + 2], acc[4 * d4 + 3]);
        *(float4*)&part[w][lane][4 * d4] = t;
    }
    part[w][lane][64] = l;
    __syncthreads();

    // combine: thread handles 16 consecutive output floats of the tile
    const int rl = threadIdx.x >> 2;          // row within tile
    const int d0 = (threadIdx.x & 3) * 16;    // dim start
    const float ltot = part[0][rl][64] + part[1][rl][64] +
                       part[2][rl][64] + part[3][rl][64];
    const float inv = 1.f / ltot;
    float* __restrict__ orow =
        out + ((size_t)b * T_DIM + t0) * H_DIM + (size_t)threadIdx.x * 16;
#pragma unroll
    for (int i = 0; i < 4; ++i) {
        const float4 s0 = *(const float4*)&part[0][rl][d0 + 4 * i];
        const float4 s1 = *(const float4*)&part[1][rl][d0 + 4 * i];
        const float4 s2 = *(const float4*)&part[2][rl][d0 + 4 * i];
        const float4 s3 = *(const float4*)&part[3][rl][d0 + 4 * i];
        float4 o;
        o.x = (s0.x + s1.x + s2.x + s3.x) * inv;
        o.y = (s0.y + s1.y + s2.y + s3.y) * inv;
        o.z = (s0.z + s1.z + s2.z + s3.z) * inv;
        o.w = (s0.w + s1.w + s2.w + s3.w) * inv;
        *(float4*)(orow + 4 * i) = o;
    }
}

extern "C" void kernel_launch(void* const* d_in, const int* in_sizes, int n_in,
                              void* d_out, int out_size, void* d_ws, size_t ws_size,
                              hipStream_t stream) {
    const float* x  = (const float*)d_in[0];
    const float* Wq = (const float*)d_in[1];
    const float* bq = (const float*)d_in[2];
    const float* Wk = (const float*)d_in[3];
    const float* bk = (const float*)d_in[4];
    const float* Wv = (const float*)d_in[5];
    const float* bv = (const float*)d_in[6];
    float* out = (float*)d_out;

    const size_t rows = (size_t)B_DIM * T_DIM;        // 16384
    float* q = (float*)d_ws;                          // rows*64 floats
    float* k = q + rows * H_DIM;
    float* v = k + rows * H_DIM;

    qkv_proj<<<dim3(1024, 3), 256, 0, stream>>>(x, Wq, bq, Wk, bk, Wv, bv, q, k, v);
    attn_fwd<<<dim3(64, 4), 256, 0, stream>>>(q, k, v, out);
}

// Round 2
// 172.573 us; speedup vs baseline: 8.9024x; 8.9024x over previous
//
#include <hip/hip_runtime.h>
#include <hip/hip_bf16.h>

#define T_DIM 4096
#define C_DIM 1024
#define H_DIM 64
#define B_DIM 4

typedef __attribute__((ext_vector_type(8))) short short8v;
typedef __attribute__((ext_vector_type(4))) short short4v;
typedef __attribute__((ext_vector_type(4))) float float4v;

__device__ __forceinline__ unsigned short f2bf(float f) {
    __hip_bfloat16 h = __float2bfloat16(f);
    return *reinterpret_cast<unsigned short*>(&h);
}
__device__ __forceinline__ float bf2f(unsigned short u) {
    __hip_bfloat16 h = *reinterpret_cast<__hip_bfloat16*>(&u);
    return __bfloat162float(h);
}

// ---------------------------------------------------------------------------
// W prep: Wm[k][col] f32 -> wt[(m*64+col)*1024 + k] bf16 (B-frag friendly)
// ---------------------------------------------------------------------------
__global__ __launch_bounds__(256) void wprep(
    const float* __restrict__ Wq, const float* __restrict__ Wk,
    const float* __restrict__ Wv, unsigned short* __restrict__ wt)
{
    const int tid = blockIdx.x * 256 + threadIdx.x;   // 0..196607
    const int k   = tid & 1023;
    const int col = (tid >> 10) & 63;
    const int m   = tid >> 16;
    const float* __restrict__ W = (m == 0) ? Wq : (m == 1) ? Wk : Wv;
    wt[tid] = f2bf(W[k * 64 + col]);
}

// ---------------------------------------------------------------------------
// QKV projection via MFMA. grid 256 blocks x 256 thr (4 waves).
// Wave w: rows [blk*64 + w*16, +16), all 192 output cols (3 matrices x 64).
// q output is pre-scaled by (C^-0.5 * log2 e) so attn uses exp2 directly.
// v output is stored transposed: vT[b][h][t].
// ---------------------------------------------------------------------------
__global__ __launch_bounds__(256) void qkv_mfma(
    const float* __restrict__ x, const unsigned short* __restrict__ wt,
    const float* __restrict__ bq, const float* __restrict__ bk,
    const float* __restrict__ bv,
    unsigned short* __restrict__ qb, unsigned short* __restrict__ kmat,
    unsigned short* __restrict__ vT)
{
    const int w    = threadIdx.x >> 6;
    const int lane = threadIdx.x & 63;
    const int l15  = lane & 15;
    const int g    = lane >> 4;
    const int r0   = blockIdx.x * 64 + w * 16;
    const float* __restrict__ xrow = x + (size_t)(r0 + l15) * C_DIM;

    float4v acc[3][4];
#pragma unroll
    for (int m = 0; m < 3; ++m)
#pragma unroll
        for (int cg = 0; cg < 4; ++cg)
            acc[m][cg] = (float4v){0.f, 0.f, 0.f, 0.f};

    for (int kb = 0; kb < C_DIM; kb += 32) {
        const float4* xp = (const float4*)(xrow + kb + 8 * g);
        const float4 x0 = xp[0];
        const float4 x1 = xp[1];
        short8v a;
        a[0] = (short)f2bf(x0.x); a[1] = (short)f2bf(x0.y);
        a[2] = (short)f2bf(x0.z); a[3] = (short)f2bf(x0.w);
        a[4] = (short)f2bf(x1.x); a[5] = (short)f2bf(x1.y);
        a[6] = (short)f2bf(x1.z); a[7] = (short)f2bf(x1.w);
#pragma unroll
        for (int m = 0; m < 3; ++m) {
#pragma unroll
            for (int cg = 0; cg < 4; ++cg) {
                const short8v bfrag = *(const short8v*)(
                    wt + (size_t)(m * 64 + cg * 16 + l15) * 1024 + kb + 8 * g);
                acc[m][cg] = __builtin_amdgcn_mfma_f32_16x16x32_bf16(
                    a, bfrag, acc[m][cg], 0, 0, 0);
            }
        }
    }

    const float qscale = 0.03125f * 1.44269504088896f;  // C^-0.5 * log2(e)
#pragma unroll
    for (int m = 0; m < 3; ++m) {
        const float* __restrict__ bias = (m == 0) ? bq : (m == 1) ? bk : bv;
#pragma unroll
        for (int cg = 0; cg < 4; ++cg) {
            const float bb = bias[cg * 16 + l15];
#pragma unroll
            for (int r = 0; r < 4; ++r) {
                float vsto = acc[m][cg][r] + bb;
                const int arow = r0 + 4 * g + r;
                if (m == 0) {
                    qb[(size_t)arow * 64 + cg * 16 + l15] = f2bf(vsto * qscale);
                } else if (m == 1) {
                    kmat[(size_t)arow * 64 + cg * 16 + l15] = f2bf(vsto);
                } else {
                    const int bb_i = arow >> 12;
                    const int t    = arow & 4095;
                    vT[((size_t)bb_i * 64 + cg * 16 + l15) * T_DIM + t] = f2bf(vsto);
                }
            }
        }
    }
}

// ---------------------------------------------------------------------------
// Causal attention via MFMA, no max-subtraction (|s| <~ 1.5 after scaling).
// grid 1024 blocks x 128 thr (2 waves). Block = (b, 16-row q tile), longest
// tiles first. Swapped QK^T: D[kv][q] so the P fragment feeds PV's A operand
// with zero shuffles (consistent (g,slot)->k map on both sides).
// Waves split kv into even/odd 32-chunks; 2-way combine through LDS.
// ---------------------------------------------------------------------------
__global__ __launch_bounds__(128) void attn_mfma(
    const unsigned short* __restrict__ qb, const unsigned short* __restrict__ kmat,
    const unsigned short* __restrict__ vT, float* __restrict__ out)
{
    __shared__ float partO[2][16][68];
    __shared__ float partl[2][16];

    const int w    = threadIdx.x >> 6;
    const int lane = threadIdx.x & 63;
    const int l15  = lane & 15;
    const int g    = lane >> 4;
    const int blk  = blockIdx.x;
    const int t    = 255 - (blk >> 2);   // q tile, longest first
    const int b    = blk & 3;
    const int q0   = t * 16;
    const int kv_end = q0 + 16;
    const int qabs = q0 + l15;

    const unsigned short* __restrict__ qrow = qb + ((size_t)b * T_DIM + q0 + l15) * 64;
    const short8v qf0 = *(const short8v*)(qrow + 8 * g);
    const short8v qf1 = *(const short8v*)(qrow + 32 + 8 * g);
    const unsigned short* __restrict__ kbase = kmat + (size_t)b * T_DIM * 64;
    const unsigned short* __restrict__ vbase = vT + (size_t)b * 64 * T_DIM;

    float4v acc[4];
#pragma unroll
    for (int f = 0; f < 4; ++f) acc[f] = (float4v){0.f, 0.f, 0.f, 0.f};
    float lsum = 0.f;

    for (int kv0 = w * 32; kv0 < kv_end; kv0 += 64) {
        // K A-fragments: rows kv0+l15 and kv0+16+l15, h halves
        const unsigned short* kr0 = kbase + (size_t)(kv0 + l15) * 64 + 8 * g;
        const unsigned short* kr1 = kbase + (size_t)(kv0 + 16 + l15) * 64 + 8 * g;
        const short8v ka0 = *(const short8v*)kr0;
        const short8v ka1 = *(const short8v*)(kr0 + 32);
        const short8v ka2 = *(const short8v*)kr1;
        const short8v ka3 = *(const short8v*)(kr1 + 32);

        const float4v z = (float4v){0.f, 0.f, 0.f, 0.f};
        float4v slo = __builtin_amdgcn_mfma_f32_16x16x32_bf16(ka0, qf0, z, 0, 0, 0);
        slo = __builtin_amdgcn_mfma_f32_16x16x32_bf16(ka1, qf1, slo, 0, 0, 0);
        float4v shi = __builtin_amdgcn_mfma_f32_16x16x32_bf16(ka2, qf0, z, 0, 0, 0);
        shi = __builtin_amdgcn_mfma_f32_16x16x32_bf16(ka3, qf1, shi, 0, 0, 0);

        // mask + exp2 + pack P to bf16 (slots 0-3: kv0+4g+r, 4-7: +16)
        short8v pa;
#pragma unroll
        for (int r = 0; r < 4; ++r) {
            const int kvlo = kv0 + 4 * g + r;
            const float plo = (kvlo <= qabs) ? exp2f(slo[r]) : 0.f;
            const float phi = (kvlo + 16 <= qabs) ? exp2f(shi[r]) : 0.f;
            const unsigned short ulo = f2bf(plo);
            const unsigned short uhi = f2bf(phi);
            pa[r]     = (short)ulo;
            pa[4 + r] = (short)uhi;
            lsum += bf2f(ulo) + bf2f(uhi);
        }

        // V B-fragments from vT (two contiguous 8B runs per fragment) + PV
#pragma unroll
        for (int f = 0; f < 4; ++f) {
            const unsigned short* vcol = vbase + (size_t)(f * 16 + l15) * T_DIM;
            const short4v vlo = *(const short4v*)(vcol + kv0 + 4 * g);
            const short4v vhi = *(const short4v*)(vcol + kv0 + 16 + 4 * g);
            short8v vb;
            vb[0] = vlo[0]; vb[1] = vlo[1]; vb[2] = vlo[2]; vb[3] = vlo[3];
            vb[4] = vhi[0]; vb[5] = vhi[1]; vb[6] = vhi[2]; vb[7] = vhi[3];
            acc[f] = __builtin_amdgcn_mfma_f32_16x16x32_bf16(pa, vb, acc[f], 0, 0, 0);
        }
    }

    // per-wave l reduction: lanes {l15, l15+16, +32, +48} hold same q
    lsum += __shfl_xor(lsum, 16);
    lsum += __shfl_xor(lsum, 32);

#pragma unroll
    for (int f = 0; f < 4; ++f)
#pragma unroll
        for (int r = 0; r < 4; ++r)
            partO[w][4 * g + r][f * 16 + l15] = acc[f][r];
    if (lane < 16) partl[w][lane] = lsum;
    __syncthreads();

    // combine + normalize: 128 threads, 8 floats each
    const int row = threadIdx.x >> 3;
    const int c0  = (threadIdx.x & 7) * 8;
    const float inv = 1.f / (partl[0][row] + partl[1][row]);
    float* __restrict__ orow = out + ((size_t)b * T_DIM + q0 + row) * 64 + c0;
#pragma unroll
    for (int j = 0; j < 8; ++j)
        orow[j] = (partO[0][row][c0 + j] + partO[1][row][c0 + j]) * inv;
}

extern "C" void kernel_launch(void* const* d_in, const int* in_sizes, int n_in,
                              void* d_out, int out_size, void* d_ws, size_t ws_size,
                              hipStream_t stream) {
    const float* x  = (const float*)d_in[0];
    const float* Wq = (const float*)d_in[1];
    const float* bq = (const float*)d_in[2];
    const float* Wk = (const float*)d_in[3];
    const float* bk = (const float*)d_in[4];
    const float* Wv = (const float*)d_in[5];
    const float* bv = (const float*)d_in[6];
    float* out = (float*)d_out;

    const size_t rows = (size_t)B_DIM * T_DIM;            // 16384
    char* ws = (char*)d_ws;
    unsigned short* qb   = (unsigned short*)ws;                       // 2 MB
    unsigned short* kmat = qb + rows * H_DIM;                         // 2 MB
    unsigned short* vT   = kmat + rows * H_DIM;                       // 2 MB
    unsigned short* wt   = vT + rows * H_DIM;                         // 384 KB

    wprep<<<768, 256, 0, stream>>>(Wq, Wk, Wv, wt);
    qkv_mfma<<<256, 256, 0, stream>>>(x, wt, bq, bk, bv, qb, kmat, vT);
    attn_mfma<<<1024, 128, 0, stream>>>(qb, kmat, vT, out);
}

// Round 3
// 123.066 us; speedup vs baseline: 12.4836x; 1.4023x over previous
//
#include <hip/hip_runtime.h>
#include <hip/hip_bf16.h>

#define T_DIM 4096
#define C_DIM 1024
#define H_DIM 64
#define B_DIM 4

typedef __attribute__((ext_vector_type(8))) short short8v;
typedef __attribute__((ext_vector_type(4))) short short4v;
typedef __attribute__((ext_vector_type(4))) float float4v;

__device__ __forceinline__ unsigned short f2bf(float f) {
    __hip_bfloat16 h = __float2bfloat16(f);
    return *reinterpret_cast<unsigned short*>(&h);
}
__device__ __forceinline__ float bf2f(unsigned short u) {
    __hip_bfloat16 h = *reinterpret_cast<__hip_bfloat16*>(&u);
    return __bfloat162float(h);
}

// ---------------------------------------------------------------------------
// W prep: Wm[k][col] f32 -> wt[(m*64+col)*1024 + k] bf16 (B-frag friendly)
// ---------------------------------------------------------------------------
__global__ __launch_bounds__(256) void wprep(
    const float* __restrict__ Wq, const float* __restrict__ Wk,
    const float* __restrict__ Wv, unsigned short* __restrict__ wt)
{
    const int tid = blockIdx.x * 256 + threadIdx.x;   // 0..196607
    const int k   = tid & 1023;
    const int col = (tid >> 10) & 63;
    const int m   = tid >> 16;
    const float* __restrict__ W = (m == 0) ? Wq : (m == 1) ? Wk : Wv;
    wt[tid] = f2bf(W[k * 64 + col]);
}

// ---------------------------------------------------------------------------
// QKV projection via MFMA. 3072 waves = (1024 row-tiles x 3 matrices):
// wave = 16 rows x 64 cols of ONE matrix -> 3 waves/SIMD for latency hiding.
// The 3 m-waves of a row-tile are consecutive (same block) -> x reads L1-hit.
// q pre-scaled by C^-0.5*log2(e); v stored transposed vT[b][h][t].
// ---------------------------------------------------------------------------
__global__ __launch_bounds__(256) void qkv_mfma(
    const float* __restrict__ x, const unsigned short* __restrict__ wt,
    const float* __restrict__ bq, const float* __restrict__ bk,
    const float* __restrict__ bv,
    unsigned short* __restrict__ qb, unsigned short* __restrict__ kmat,
    unsigned short* __restrict__ vT)
{
    const int lane = threadIdx.x & 63;
    const int l15  = lane & 15;
    const int g    = lane >> 4;
    const int W    = blockIdx.x * 4 + (threadIdx.x >> 6);  // 0..3071
    const int rt   = W / 3;                                // row tile 0..1023
    const int m    = W - rt * 3;                           // matrix 0..2
    const int r0   = rt * 16;

    const float* __restrict__ xrow = x + (size_t)(r0 + l15) * C_DIM;
    const unsigned short* __restrict__ wb = wt + (size_t)m * 64 * 1024;

    float4v acc[4];
#pragma unroll
    for (int cg = 0; cg < 4; ++cg) acc[cg] = (float4v){0.f, 0.f, 0.f, 0.f};

    for (int kb = 0; kb < C_DIM; kb += 32) {
        const float4* xp = (const float4*)(xrow + kb + 8 * g);
        const float4 x0 = xp[0];
        const float4 x1 = xp[1];
        short8v a;
        a[0] = (short)f2bf(x0.x); a[1] = (short)f2bf(x0.y);
        a[2] = (short)f2bf(x0.z); a[3] = (short)f2bf(x0.w);
        a[4] = (short)f2bf(x1.x); a[5] = (short)f2bf(x1.y);
        a[6] = (short)f2bf(x1.z); a[7] = (short)f2bf(x1.w);
#pragma unroll
        for (int cg = 0; cg < 4; ++cg) {
            const short8v bfrag = *(const short8v*)(
                wb + (size_t)(cg * 16 + l15) * 1024 + kb + 8 * g);
            acc[cg] = __builtin_amdgcn_mfma_f32_16x16x32_bf16(a, bfrag, acc[cg], 0, 0, 0);
        }
    }

    const float* __restrict__ bias = (m == 0) ? bq : (m == 1) ? bk : bv;
    const float qscale = 0.03125f * 1.44269504088896f;  // C^-0.5 * log2(e)
#pragma unroll
    for (int cg = 0; cg < 4; ++cg) {
        const float bb = bias[cg * 16 + l15];
#pragma unroll
        for (int r = 0; r < 4; ++r) {
            const float vsto = acc[cg][r] + bb;
            const int arow = r0 + 4 * g + r;
            if (m == 0) {
                qb[(size_t)arow * 64 + cg * 16 + l15] = f2bf(vsto * qscale);
            } else if (m == 1) {
                kmat[(size_t)arow * 64 + cg * 16 + l15] = f2bf(vsto);
            } else {
                const int bb_i = arow >> 12;
                const int t    = arow & 4095;
                vT[((size_t)bb_i * 64 + cg * 16 + l15) * T_DIM + t] = f2bf(vsto);
            }
        }
    }
}

// ---------------------------------------------------------------------------
// Causal attention via MFMA, no max-subtraction (|s·log2e| < ~2, exp2 safe).
// grid 512 blocks x 256 thr. Block = 32 q-rows x (batch), 4 waves splitting
// the kv range [0, q0+32) 4-ways. Each wave handles TWO 16-row q sub-tiles ->
// K/V fragments amortized over 16 MFMA per 32-kv step.
// Block order pairs long tiles (i<256) with short ones (i>=256) so per-CU
// work is ~constant. Swapped QK^T (mfma(K,Q)) -> P feeds PV A-operand with
// zero shuffles. 4-way combine through LDS.
// ---------------------------------------------------------------------------
__global__ __launch_bounds__(256) void attn_mfma(
    const unsigned short* __restrict__ qb, const unsigned short* __restrict__ kmat,
    const unsigned short* __restrict__ vT, float* __restrict__ out)
{
    __shared__ float partO[4][32][68];
    __shared__ float partl[4][32];

    const int w    = threadIdx.x >> 6;
    const int lane = threadIdx.x & 63;
    const int l15  = lane & 15;
    const int g    = lane >> 4;
    const int i    = blockIdx.x;
    const int pair = i & 255;
    const int half = i >> 8;
    const int p2   = pair >> 2;                    // 0..63
    const int tt   = half ? p2 : 127 - p2;         // q tile (32 rows)
    const int b    = pair & 3;
    const int q0   = tt * 32;
    const int n    = tt + 1;                       // total 32-kv steps

    const unsigned short* __restrict__ qbase = qb + ((size_t)b * T_DIM + q0) * 64;
    short8v qf[2][2];
    qf[0][0] = *(const short8v*)(qbase + (size_t)l15 * 64 + 8 * g);
    qf[0][1] = *(const short8v*)(qbase + (size_t)l15 * 64 + 32 + 8 * g);
    qf[1][0] = *(const short8v*)(qbase + (size_t)(16 + l15) * 64 + 8 * g);
    qf[1][1] = *(const short8v*)(qbase + (size_t)(16 + l15) * 64 + 32 + 8 * g);

    const unsigned short* __restrict__ kbase = kmat + (size_t)b * T_DIM * 64;
    const unsigned short* __restrict__ vbase = vT + (size_t)b * 64 * T_DIM;

    float4v acc[2][4];
#pragma unroll
    for (int qt = 0; qt < 2; ++qt)
#pragma unroll
        for (int f = 0; f < 4; ++f) acc[qt][f] = (float4v){0.f, 0.f, 0.f, 0.f};
    float lsum[2] = {0.f, 0.f};

    const int rem = n & 3;
    const int cnt = (n >> 2) + (w < rem ? 1 : 0);
    const int st  = w * (n >> 2) + (w < rem ? w : rem);

    for (int s = 0; s < cnt; ++s) {
        const int kv0 = (st + s) * 32;

        const unsigned short* kr0 = kbase + (size_t)(kv0 + l15) * 64 + 8 * g;
        const unsigned short* kr1 = kr0 + 16 * 64;
        const short8v ka0 = *(const short8v*)kr0;
        const short8v ka1 = *(const short8v*)(kr0 + 32);
        const short8v ka2 = *(const short8v*)kr1;
        const short8v ka3 = *(const short8v*)(kr1 + 32);

        short8v vb4[4];
#pragma unroll
        for (int f = 0; f < 4; ++f) {
            const unsigned short* vcol = vbase + (size_t)(f * 16 + l15) * T_DIM + kv0;
            const short4v vlo = *(const short4v*)(vcol + 4 * g);
            const short4v vhi = *(const short4v*)(vcol + 16 + 4 * g);
            short8v t;
            t[0] = vlo[0]; t[1] = vlo[1]; t[2] = vlo[2]; t[3] = vlo[3];
            t[4] = vhi[0]; t[5] = vhi[1]; t[6] = vhi[2]; t[7] = vhi[3];
            vb4[f] = t;
        }

#pragma unroll
        for (int qt = 0; qt < 2; ++qt) {
            const float4v z = (float4v){0.f, 0.f, 0.f, 0.f};
            float4v slo = __builtin_amdgcn_mfma_f32_16x16x32_bf16(ka0, qf[qt][0], z, 0, 0, 0);
            slo = __builtin_amdgcn_mfma_f32_16x16x32_bf16(ka1, qf[qt][1], slo, 0, 0, 0);
            float4v shi = __builtin_amdgcn_mfma_f32_16x16x32_bf16(ka2, qf[qt][0], z, 0, 0, 0);
            shi = __builtin_amdgcn_mfma_f32_16x16x32_bf16(ka3, qf[qt][1], shi, 0, 0, 0);

            const int qabs = q0 + 16 * qt + l15;
            short8v pa;
            float ls = 0.f;
#pragma unroll
            for (int r = 0; r < 4; ++r) {
                const int kvlo = kv0 + 4 * g + r;
                const float plo = (kvlo <= qabs) ? exp2f(slo[r]) : 0.f;
                const float phi = (kvlo + 16 <= qabs) ? exp2f(shi[r]) : 0.f;
                const unsigned short ulo = f2bf(plo);
                const unsigned short uhi = f2bf(phi);
                pa[r]     = (short)ulo;
                pa[4 + r] = (short)uhi;
                ls += bf2f(ulo) + bf2f(uhi);
            }
            lsum[qt] += ls;
#pragma unroll
            for (int f = 0; f < 4; ++f)
                acc[qt][f] = __builtin_amdgcn_mfma_f32_16x16x32_bf16(pa, vb4[f], acc[qt][f], 0, 0, 0);
        }
    }

    // per-wave l reduction across the 4 g-groups (same l15 => same q row)
#pragma unroll
    for (int qt = 0; qt < 2; ++qt) {
        lsum[qt] += __shfl_xor(lsum[qt], 16);
        lsum[qt] += __shfl_xor(lsum[qt], 32);
    }

#pragma unroll
    for (int qt = 0; qt < 2; ++qt)
#pragma unroll
        for (int f = 0; f < 4; ++f)
#pragma unroll
            for (int r = 0; r < 4; ++r)
                partO[w][16 * qt + 4 * g + r][16 * f + l15] = acc[qt][f][r];
    if (g == 0) {
        partl[w][l15]      = lsum[0];
        partl[w][16 + l15] = lsum[1];
    }
    __syncthreads();

    // combine + normalize: 256 threads, 8 floats each (32 rows x 64 cols)
    const int row = threadIdx.x >> 3;
    const int c0  = (threadIdx.x & 7) * 8;
    const float inv = 1.f / (partl[0][row] + partl[1][row] + partl[2][row] + partl[3][row]);
    float* __restrict__ orow = out + ((size_t)b * T_DIM + q0 + row) * 64 + c0;
#pragma unroll
    for (int h = 0; h < 2; ++h) {
        const float4 s0 = *(const float4*)&partO[0][row][c0 + 4 * h];
        const float4 s1 = *(const float4*)&partO[1][row][c0 + 4 * h];
        const float4 s2 = *(const float4*)&partO[2][row][c0 + 4 * h];
        const float4 s3 = *(const float4*)&partO[3][row][c0 + 4 * h];
        float4 o;
        o.x = (s0.x + s1.x + s2.x + s3.x) * inv;
        o.y = (s0.y + s1.y + s2.y + s3.y) * inv;
        o.z = (s0.z + s1.z + s2.z + s3.z) * inv;
        o.w = (s0.w + s1.w + s2.w + s3.w) * inv;
        *(float4*)(orow + 4 * h) = o;
    }
}

extern "C" void kernel_launch(void* const* d_in, const int* in_sizes, int n_in,
                              void* d_out, int out_size, void* d_ws, size_t ws_size,
                              hipStream_t stream) {
    const float* x  = (const float*)d_in[0];
    const float* Wq = (const float*)d_in[1];
    const float* bq = (const float*)d_in[2];
    const float* Wk = (const float*)d_in[3];
    const float* bk = (const float*)d_in[4];
    const float* Wv = (const float*)d_in[5];
    const float* bv = (const float*)d_in[6];
    float* out = (float*)d_out;

    const size_t rows = (size_t)B_DIM * T_DIM;            // 16384
    char* ws = (char*)d_ws;
    unsigned short* qb   = (unsigned short*)ws;                       // 2 MB
    unsigned short* kmat = qb + rows * H_DIM;                         // 2 MB
    unsigned short* vT   = kmat + rows * H_DIM;                       // 2 MB
    unsigned short* wt   = vT + rows * H_DIM;                         // 384 KB

    wprep<<<768, 256, 0, stream>>>(Wq, Wk, Wv, wt);
    qkv_mfma<<<768, 256, 0, stream>>>(x, wt, bq, bk, bv, qb, kmat, vT);
    attn_mfma<<<512, 256, 0, stream>>>(qb, kmat, vT, out);
}

// Round 4
// 109.584 us; speedup vs baseline: 14.0194x; 1.1230x over previous
//
#include <hip/hip_runtime.h>
#include <hip/hip_bf16.h>

#define T_DIM 4096
#define C_DIM 1024
#define H_DIM 64
#define B_DIM 4

typedef __attribute__((ext_vector_type(8))) short short8v;
typedef __attribute__((ext_vector_type(4))) short short4v;
typedef __attribute__((ext_vector_type(4))) float float4v;

__device__ __forceinline__ unsigned short f2bf(float f) {
    __hip_bfloat16 h = __float2bfloat16(f);
    return *reinterpret_cast<unsigned short*>(&h);
}
__device__ __forceinline__ float bf2f(unsigned short u) {
    __hip_bfloat16 h = *reinterpret_cast<__hip_bfloat16*>(&u);
    return __bfloat162float(h);
}

// permuted position within a 32-row block for V storage: slot p holds kv row
// sigma(p) with sigma(8g+j) = 4g+j (j<4) | 16+4g+(j-4) (j>=4). Inverse:
__device__ __forceinline__ int vperm(int t5) {
    return ((t5 & 12) << 1) | (t5 & 3) | ((t5 & 16) >> 2);
}

// ---------------------------------------------------------------------------
// W prep: Wm[k][col] f32 -> wt[(m*64+col)*1024 + k] bf16 (B-frag friendly)
// ---------------------------------------------------------------------------
__global__ __launch_bounds__(256) void wprep(
    const float* __restrict__ Wq, const float* __restrict__ Wk,
    const float* __restrict__ Wv, unsigned short* __restrict__ wt)
{
    const int tid = blockIdx.x * 256 + threadIdx.x;   // 0..196607
    const int k   = tid & 1023;
    const int col = (tid >> 10) & 63;
    const int m   = tid >> 16;
    const float* __restrict__ W = (m == 0) ? Wq : (m == 1) ? Wk : Wv;
    wt[tid] = f2bf(W[k * 64 + col]);
}

// ---------------------------------------------------------------------------
// QKV projection via MFMA, K-split. Block(256thr) = one (16-row tile, matrix);
// 4 waves each take a 256-wide K chunk; LDS combine. Grid = 3072 blocks ->
// 6+ blocks/CU for memory-level parallelism. bid->(rt,m) is XCD-aware: the 3
// m-blocks of one rt are 8 apart (same XCD, adjacent dispatch) -> x read once.
// q pre-scaled by C^-0.5*log2(e); v stored h-major with vperm'd t (16B PV frags).
// ---------------------------------------------------------------------------
__global__ __launch_bounds__(256, 6) void qkv_mfma(
    const float* __restrict__ x, const unsigned short* __restrict__ wt,
    const float* __restrict__ bq, const float* __restrict__ bk,
    const float* __restrict__ bv,
    unsigned short* __restrict__ qb, unsigned short* __restrict__ kmat,
    unsigned short* __restrict__ vP)
{
    __shared__ float pO[4][16][68];

    const int lane = threadIdx.x & 63;
    const int w    = threadIdx.x >> 6;
    const int l15  = lane & 15;
    const int g    = lane >> 4;

    const int bid = blockIdx.x;            // 0..3071
    const int c   = bid / 24;              // 128 chunks
    const int cc  = bid - 24 * c;
    const int rt  = 8 * c + (cc & 7);      // row tile 0..1023
    const int m   = cc >> 3;               // matrix 0..2
    const int r0  = rt * 16;

    const float* __restrict__ xrow =
        x + (size_t)(r0 + l15) * C_DIM + w * 256;
    const unsigned short* __restrict__ wb =
        wt + (size_t)m * 64 * 1024 + w * 256;

    float4v acc[4];
#pragma unroll
    for (int cg = 0; cg < 4; ++cg) acc[cg] = (float4v){0.f, 0.f, 0.f, 0.f};

#pragma unroll
    for (int kb = 0; kb < 256; kb += 32) {
        const float4* xp = (const float4*)(xrow + kb + 8 * g);
        const float4 x0 = xp[0];
        const float4 x1 = xp[1];
        short8v a;
        a[0] = (short)f2bf(x0.x); a[1] = (short)f2bf(x0.y);
        a[2] = (short)f2bf(x0.z); a[3] = (short)f2bf(x0.w);
        a[4] = (short)f2bf(x1.x); a[5] = (short)f2bf(x1.y);
        a[6] = (short)f2bf(x1.z); a[7] = (short)f2bf(x1.w);
#pragma unroll
        for (int cg = 0; cg < 4; ++cg) {
            const short8v bfrag = *(const short8v*)(
                wb + (size_t)(cg * 16 + l15) * 1024 + kb + 8 * g);
            acc[cg] = __builtin_amdgcn_mfma_f32_16x16x32_bf16(a, bfrag, acc[cg], 0, 0, 0);
        }
    }

#pragma unroll
    for (int cg = 0; cg < 4; ++cg)
#pragma unroll
        for (int r = 0; r < 4; ++r)
            pO[w][4 * g + r][cg * 16 + l15] = acc[cg][r];
    __syncthreads();

    // combine 4 K-partials + bias + store; thread = (row, 4 cols)
    const int row = threadIdx.x >> 4;          // 0..15
    const int c0  = (threadIdx.x & 15) * 4;    // 0..60
    const float4 s0 = *(const float4*)&pO[0][row][c0];
    const float4 s1 = *(const float4*)&pO[1][row][c0];
    const float4 s2 = *(const float4*)&pO[2][row][c0];
    const float4 s3 = *(const float4*)&pO[3][row][c0];
    const float* __restrict__ bias = (m == 0) ? bq : (m == 1) ? bk : bv;
    const float4 bb = *(const float4*)(bias + c0);
    float v0 = s0.x + s1.x + s2.x + s3.x + bb.x;
    float v1 = s0.y + s1.y + s2.y + s3.y + bb.y;
    float v2 = s0.z + s1.z + s2.z + s3.z + bb.z;
    float v3 = s0.w + s1.w + s2.w + s3.w + bb.w;

    const int arow = r0 + row;
    if (m == 0) {
        const float qs = 0.03125f * 1.44269504088896f;  // C^-0.5 * log2(e)
        short4v q4;
        q4[0] = (short)f2bf(v0 * qs); q4[1] = (short)f2bf(v1 * qs);
        q4[2] = (short)f2bf(v2 * qs); q4[3] = (short)f2bf(v3 * qs);
        *(short4v*)(qb + (size_t)arow * 64 + c0) = q4;
    } else if (m == 1) {
        short4v k4;
        k4[0] = (short)f2bf(v0); k4[1] = (short)f2bf(v1);
        k4[2] = (short)f2bf(v2); k4[3] = (short)f2bf(v3);
        *(short4v*)(kmat + (size_t)arow * 64 + c0) = k4;
    } else {
        const int b_i = arow >> 12;
        const int t   = arow & 4095;
        const int tp  = (t & ~31) | vperm(t & 31);
        const float vv[4] = {v0, v1, v2, v3};
#pragma unroll
        for (int j = 0; j < 4; ++j)
            vP[((size_t)b_i * 64 + c0 + j) * T_DIM + tp] = f2bf(vv[j]);
    }
}

// ---------------------------------------------------------------------------
// Causal attention via MFMA, no max-subtraction (|s*log2e| < ~2, exp2 safe).
// grid 512 x 512 thr (8 waves). Block = 32 q-rows x batch; 8 waves split the
// kv range 8 ways; each wave does TWO 16-row q sub-tiles (16 MFMA / 8 loads
// per 32-kv step; V frags are single 16B loads thanks to vperm layout).
// Complementary pairing: block i (long) and i+256 (short) land on the same CU
// -> every CU gets ~129 steps. 8-way combine through LDS.
// ---------------------------------------------------------------------------
__global__ __launch_bounds__(512, 4) void attn_mfma(
    const unsigned short* __restrict__ qb, const unsigned short* __restrict__ kmat,
    const unsigned short* __restrict__ vP, float* __restrict__ out)
{
    __shared__ float partO[8][32][68];
    __shared__ float partl[8][32];

    const int w    = threadIdx.x >> 6;     // 0..7
    const int lane = threadIdx.x & 63;
    const int l15  = lane & 15;
    const int g    = lane >> 4;
    const int i    = blockIdx.x;
    const int p2   = (i & 255) >> 2;
    const int b    = i & 3;
    const int tt   = (i < 256) ? (127 - p2) : p2;
    const int q0   = tt * 32;
    const int n    = tt + 1;               // 32-kv steps total

    const unsigned short* __restrict__ qbase = qb + ((size_t)b * T_DIM + q0) * 64;
    short8v qf[2][2];
    qf[0][0] = *(const short8v*)(qbase + (size_t)l15 * 64 + 8 * g);
    qf[0][1] = *(const short8v*)(qbase + (size_t)l15 * 64 + 32 + 8 * g);
    qf[1][0] = *(const short8v*)(qbase + (size_t)(16 + l15) * 64 + 8 * g);
    qf[1][1] = *(const short8v*)(qbase + (size_t)(16 + l15) * 64 + 32 + 8 * g);

    const unsigned short* __restrict__ kbase = kmat + (size_t)b * T_DIM * 64;
    const unsigned short* __restrict__ vbase = vP + (size_t)b * 64 * T_DIM;

    float4v acc[2][4];
#pragma unroll
    for (int qt = 0; qt < 2; ++qt)
#pragma unroll
        for (int f = 0; f < 4; ++f) acc[qt][f] = (float4v){0.f, 0.f, 0.f, 0.f};
    float lsum[2] = {0.f, 0.f};

    const int rem = n & 7;
    const int cnt = (n >> 3) + (w < rem ? 1 : 0);
    const int st  = w * (n >> 3) + (w < rem ? w : rem);

    for (int s = 0; s < cnt; ++s) {
        const int kv0 = (st + s) * 32;

        const unsigned short* kr0 = kbase + (size_t)(kv0 + l15) * 64 + 8 * g;
        const unsigned short* kr1 = kr0 + 16 * 64;
        const short8v ka0 = *(const short8v*)kr0;
        const short8v ka1 = *(const short8v*)(kr0 + 32);
        const short8v ka2 = *(const short8v*)kr1;
        const short8v ka3 = *(const short8v*)(kr1 + 32);

        short8v vb4[4];
#pragma unroll
        for (int f = 0; f < 4; ++f)
            vb4[f] = *(const short8v*)(
                vbase + (size_t)(f * 16 + l15) * T_DIM + kv0 + 8 * g);

#pragma unroll
        for (int qt = 0; qt < 2; ++qt) {
            const float4v z = (float4v){0.f, 0.f, 0.f, 0.f};
            float4v slo = __builtin_amdgcn_mfma_f32_16x16x32_bf16(ka0, qf[qt][0], z, 0, 0, 0);
            slo = __builtin_amdgcn_mfma_f32_16x16x32_bf16(ka1, qf[qt][1], slo, 0, 0, 0);
            float4v shi = __builtin_amdgcn_mfma_f32_16x16x32_bf16(ka2, qf[qt][0], z, 0, 0, 0);
            shi = __builtin_amdgcn_mfma_f32_16x16x32_bf16(ka3, qf[qt][1], shi, 0, 0, 0);

            const int qabs = q0 + 16 * qt + l15;
            short8v pa;
            float ls = 0.f;
#pragma unroll
            for (int r = 0; r < 4; ++r) {
                const int kvlo = kv0 + 4 * g + r;
                const float plo = (kvlo <= qabs) ? exp2f(slo[r]) : 0.f;
                const float phi = (kvlo + 16 <= qabs) ? exp2f(shi[r]) : 0.f;
                const unsigned short ulo = f2bf(plo);
                const unsigned short uhi = f2bf(phi);
                pa[r]     = (short)ulo;
                pa[4 + r] = (short)uhi;
                ls += bf2f(ulo) + bf2f(uhi);
            }
            lsum[qt] += ls;
#pragma unroll
            for (int f = 0; f < 4; ++f)
                acc[qt][f] = __builtin_amdgcn_mfma_f32_16x16x32_bf16(pa, vb4[f], acc[qt][f], 0, 0, 0);
        }
    }

    // per-wave l reduction across g groups (lanes with same l15 share q row)
#pragma unroll
    for (int qt = 0; qt < 2; ++qt) {
        lsum[qt] += __shfl_xor(lsum[qt], 16);
        lsum[qt] += __shfl_xor(lsum[qt], 32);
    }

#pragma unroll
    for (int qt = 0; qt < 2; ++qt)
#pragma unroll
        for (int f = 0; f < 4; ++f)
#pragma unroll
            for (int r = 0; r < 4; ++r)
                partO[w][16 * qt + 4 * g + r][16 * f + l15] = acc[qt][f][r];
    if (g == 0) {
        partl[w][l15]      = lsum[0];
        partl[w][16 + l15] = lsum[1];
    }
    __syncthreads();

    // combine + normalize: 512 threads, one float4 each (32 rows x 64 cols)
    const int row = threadIdx.x >> 4;          // 0..31
    const int c0  = (threadIdx.x & 15) * 4;
    float lt = 0.f;
#pragma unroll
    for (int ww = 0; ww < 8; ++ww) lt += partl[ww][row];
    const float inv = 1.f / lt;
    float4 o = make_float4(0.f, 0.f, 0.f, 0.f);
#pragma unroll
    for (int ww = 0; ww < 8; ++ww) {
        const float4 s = *(const float4*)&partO[ww][row][c0];
        o.x += s.x; o.y += s.y; o.z += s.z; o.w += s.w;
    }
    o.x *= inv; o.y *= inv; o.z *= inv; o.w *= inv;
    *(float4*)(out + ((size_t)b * T_DIM + q0 + row) * 64 + c0) = o;
}

extern "C" void kernel_launch(void* const* d_in, const int* in_sizes, int n_in,
                              void* d_out, int out_size, void* d_ws, size_t ws_size,
                              hipStream_t stream) {
    const float* x  = (const float*)d_in[0];
    const float* Wq = (const float*)d_in[1];
    const float* bq = (const float*)d_in[2];
    const float* Wk = (const float*)d_in[3];
    const float* bk = (const float*)d_in[4];
    const float* Wv = (const float*)d_in[5];
    const float* bv = (const float*)d_in[6];
    float* out = (float*)d_out;

    const size_t rows = (size_t)B_DIM * T_DIM;            // 16384
    char* ws = (char*)d_ws;
    unsigned short* qb   = (unsigned short*)ws;                       // 2 MB
    unsigned short* kmat = qb + rows * H_DIM;                         // 2 MB
    unsigned short* vP   = kmat + rows * H_DIM;                       // 2 MB
    unsigned short* wt   = vP + rows * H_DIM;                         // 384 KB

    wprep<<<768, 256, 0, stream>>>(Wq, Wk, Wv, wt);
    qkv_mfma<<<3072, 256, 0, stream>>>(x, wt, bq, bk, bv, qb, kmat, vP);
    attn_mfma<<<512, 512, 0, stream>>>(qb, kmat, vP, out);
}

// Round 5
// 65.970 us; speedup vs baseline: 23.2881x; 1.6611x over previous
//
#include <hip/hip_runtime.h>
#include <hip/hip_bf16.h>

#define T_DIM 4096
#define C_DIM 1024
#define H_DIM 64
#define B_DIM 4

typedef __attribute__((ext_vector_type(8))) short short8v;
typedef __attribute__((ext_vector_type(4))) short short4v;
typedef __attribute__((ext_vector_type(4))) float float4v;

__device__ __forceinline__ unsigned short f2bf(float f) {
    __hip_bfloat16 h = __float2bfloat16(f);
    return *reinterpret_cast<unsigned short*>(&h);
}
__device__ __forceinline__ float bf2f(unsigned short u) {
    __hip_bfloat16 h = *reinterpret_cast<__hip_bfloat16*>(&u);
    return __bfloat162float(h);
}

// permuted position within a 32-row block for V storage: slot p holds kv row
// sigma(p); vperm maps logical kv row -> storage slot (see attn PV frag load).
__device__ __forceinline__ int vperm(int t5) {
    return ((t5 & 12) << 1) | (t5 & 3) | ((t5 & 16) >> 2);
}

#define GLL16(gsrc, ldst)                                                         \
    __builtin_amdgcn_global_load_lds(                                             \
        (const __attribute__((address_space(1))) unsigned int*)(gsrc),            \
        (__attribute__((address_space(3))) unsigned int*)(ldst), 16, 0, 0)

// ---------------------------------------------------------------------------
// W prep: Wm[k][col] f32 -> wt[(m*64+col)*1024 + k] bf16 (B-frag friendly)
// ---------------------------------------------------------------------------
__global__ __launch_bounds__(256) void wprep(
    const float* __restrict__ Wq, const float* __restrict__ Wk,
    const float* __restrict__ Wv, unsigned short* __restrict__ wt)
{
    const int tid = blockIdx.x * 256 + threadIdx.x;   // 0..196607
    const int k   = tid & 1023;
    const int col = (tid >> 10) & 63;
    const int m   = tid >> 16;
    const float* __restrict__ W = (m == 0) ? Wq : (m == 1) ? Wk : Wv;
    wt[tid] = f2bf(W[k * 64 + col]);
}

// ---------------------------------------------------------------------------
// QKV projection: LDS-staged GEMM (m97 pattern). Block = 64 rows x 192 cols,
// K-loop 16 steps of 64. 512 thr = 8 waves; wave = 16 rows x 96 cols, full K
// in-wave (no partial combine). x staged as f32 via global_load_lds width=16
// (1KB/instr coalesced), converted to bf16 after LDS read (once per element).
// LDS reads XOR-swizzled (granule ^ row) with inverse-swizzled global source
// (rule: gll dest must stay linear). Double-buffered, 2-phase schedule.
// ---------------------------------------------------------------------------
__global__ __launch_bounds__(512, 2) void qkv_gemm(
    const float* __restrict__ x, const unsigned short* __restrict__ wt,
    const float* __restrict__ bq, const float* __restrict__ bk,
    const float* __restrict__ bv,
    unsigned short* __restrict__ qb, unsigned short* __restrict__ kmat,
    unsigned short* __restrict__ vP)
{
    __shared__ __align__(16) unsigned char lx[2][16384];  // 64 rows x 64 f32
    __shared__ __align__(16) unsigned char lw[2][24576];  // 192 cols x 64 bf16

    const int t    = threadIdx.x;
    const int w    = t >> 6;
    const int lane = t & 63;
    const int l15  = lane & 15;
    const int g    = lane >> 4;
    const int r0   = blockIdx.x * 64;

    // staging source swizzle constants (per-thread)
    const int xgl = (t & 15) ^ ((t >> 4) & 15);   // x: logical granule for dest gp=t&15
    const int wgl = (t & 7) ^ ((t >> 3) & 7);     // wt: logical granule for dest gp=t&7

    const unsigned char* __restrict__ xB = (const unsigned char*)x;
    const unsigned char* __restrict__ wB = (const unsigned char*)wt;

#define STAGE(p, kb)                                                              \
    {                                                                             \
        _Pragma("unroll")                                                         \
        for (int i = 0; i < 2; ++i) {                                             \
            const unsigned char* src =                                            \
                xB + (size_t)(r0 + i * 32 + (t >> 4)) * 4096 + (kb) * 256 + xgl * 16; \
            GLL16(src, &lx[p][(i * 512 + t) * 16]);                               \
        }                                                                         \
        _Pragma("unroll")                                                         \
        for (int j = 0; j < 3; ++j) {                                             \
            const unsigned char* src =                                            \
                wB + (size_t)(j * 64 + (t >> 3)) * 2048 + (kb) * 128 + wgl * 16;  \
            GLL16(src, &lw[p][(j * 512 + t) * 16]);                               \
        }                                                                         \
    }

    const int rbase = (w & 3) * 16;     // wave's row offset within block
    const int W0    = (w >> 2) * 96;    // wave's col offset (0 or 96)

    float4v acc[6];
#pragma unroll
    for (int cg = 0; cg < 6; ++cg) acc[cg] = (float4v){0.f, 0.f, 0.f, 0.f};

    STAGE(0, 0);
    __syncthreads();

    for (int kb = 0; kb < 16; ++kb) {
        const int p = kb & 1;
        if (kb < 15) STAGE(p ^ 1, kb + 1);

        // A fragments: rows rbase+l15, k = ks*32 + 8g .. +8 (f32 -> bf16)
        const int arow = rbase + l15;
        short8v af[2];
#pragma unroll
        for (int ks = 0; ks < 2; ++ks) {
            const int Lg0 = ks * 8 + 2 * g;
            const float4 a0 = *(const float4*)&lx[p][arow * 256 + ((Lg0)     ^ l15) * 16];
            const float4 a1 = *(const float4*)&lx[p][arow * 256 + ((Lg0 + 1) ^ l15) * 16];
            short8v a;
            a[0] = (short)f2bf(a0.x); a[1] = (short)f2bf(a0.y);
            a[2] = (short)f2bf(a0.z); a[3] = (short)f2bf(a0.w);
            a[4] = (short)f2bf(a1.x); a[5] = (short)f2bf(a1.y);
            a[6] = (short)f2bf(a1.z); a[7] = (short)f2bf(a1.w);
            af[ks] = a;
        }

#pragma unroll
        for (int cg = 0; cg < 6; ++cg) {
            const int wrow = W0 + cg * 16 + l15;
#pragma unroll
            for (int ks = 0; ks < 2; ++ks) {
                const int phys = (ks * 4 + g) ^ (l15 & 7);
                const short8v bf = *(const short8v*)&lw[p][wrow * 128 + phys * 16];
                acc[cg] = __builtin_amdgcn_mfma_f32_16x16x32_bf16(af[ks], bf, acc[cg], 0, 0, 0);
            }
        }
        __syncthreads();
    }

    // epilogue: lane (l15,g) holds rows rbase+4g+rr, col W0+cg*16+l15
    const float qs = 0.03125f * 1.44269504088896f;  // C^-0.5 * log2(e)
#pragma unroll
    for (int cg = 0; cg < 6; ++cg) {
        const int cabs = W0 + cg * 16 + l15;
        const int m    = cabs >> 6;        // uniform per (w,cg)
        const int h    = cabs & 63;
        const float bb = ((m == 0) ? bq : (m == 1) ? bk : bv)[h];
#pragma unroll
        for (int rr = 0; rr < 4; ++rr) {
            const int row = r0 + rbase + 4 * g + rr;
            const float vv = acc[cg][rr] + bb;
            if (m == 0) {
                qb[(size_t)row * 64 + h] = f2bf(vv * qs);
            } else if (m == 1) {
                kmat[(size_t)row * 64 + h] = f2bf(vv);
            } else {
                const int b_i = row >> 12;
                const int tt  = row & 4095;
                const int tp  = (tt & ~31) | vperm(tt & 31);
                vP[((size_t)b_i * 64 + h) * T_DIM + tp] = f2bf(vv);
            }
        }
    }
#undef STAGE
}

// ---------------------------------------------------------------------------
// Causal attention via MFMA, no max-subtraction (|s*log2e| < ~2, exp2 safe).
// grid 512 x 512 thr (8 waves). Block = 32 q-rows x batch; 8 waves split the
// kv range 8 ways; each wave does TWO 16-row q sub-tiles (16 MFMA / 8 loads
// per 32-kv step; V frags are single 16B loads thanks to vperm layout).
// Complementary pairing: block i (long) and i+256 (short) land on the same CU
// -> every CU gets ~129 steps. 8-way combine through LDS.
// ---------------------------------------------------------------------------
__global__ __launch_bounds__(512, 4) void attn_mfma(
    const unsigned short* __restrict__ qb, const unsigned short* __restrict__ kmat,
    const unsigned short* __restrict__ vP, float* __restrict__ out)
{
    __shared__ float partO[8][32][68];
    __shared__ float partl[8][32];

    const int w    = threadIdx.x >> 6;     // 0..7
    const int lane = threadIdx.x & 63;
    const int l15  = lane & 15;
    const int g    = lane >> 4;
    const int i    = blockIdx.x;
    const int p2   = (i & 255) >> 2;
    const int b    = i & 3;
    const int tt   = (i < 256) ? (127 - p2) : p2;
    const int q0   = tt * 32;
    const int n    = tt + 1;               // 32-kv steps total

    const unsigned short* __restrict__ qbase = qb + ((size_t)b * T_DIM + q0) * 64;
    short8v qf[2][2];
    qf[0][0] = *(const short8v*)(qbase + (size_t)l15 * 64 + 8 * g);
    qf[0][1] = *(const short8v*)(qbase + (size_t)l15 * 64 + 32 + 8 * g);
    qf[1][0] = *(const short8v*)(qbase + (size_t)(16 + l15) * 64 + 8 * g);
    qf[1][1] = *(const short8v*)(qbase + (size_t)(16 + l15) * 64 + 32 + 8 * g);

    const unsigned short* __restrict__ kbase = kmat + (size_t)b * T_DIM * 64;
    const unsigned short* __restrict__ vbase = vP + (size_t)b * 64 * T_DIM;

    float4v acc[2][4];
#pragma unroll
    for (int qt = 0; qt < 2; ++qt)
#pragma unroll
        for (int f = 0; f < 4; ++f) acc[qt][f] = (float4v){0.f, 0.f, 0.f, 0.f};
    float lsum[2] = {0.f, 0.f};

    const int rem = n & 7;
    const int cnt = (n >> 3) + (w < rem ? 1 : 0);
    const int st  = w * (n >> 3) + (w < rem ? w : rem);

    for (int s = 0; s < cnt; ++s) {
        const int kv0 = (st + s) * 32;

        const unsigned short* kr0 = kbase + (size_t)(kv0 + l15) * 64 + 8 * g;
        const unsigned short* kr1 = kr0 + 16 * 64;
        const short8v ka0 = *(const short8v*)kr0;
        const short8v ka1 = *(const short8v*)(kr0 + 32);
        const short8v ka2 = *(const short8v*)kr1;
        const short8v ka3 = *(const short8v*)(kr1 + 32);

        short8v vb4[4];
#pragma unroll
        for (int f = 0; f < 4; ++f)
            vb4[f] = *(const short8v*)(
                vbase + (size_t)(f * 16 + l15) * T_DIM + kv0 + 8 * g);

#pragma unroll
        for (int qt = 0; qt < 2; ++qt) {
            const float4v z = (float4v){0.f, 0.f, 0.f, 0.f};
            float4v slo = __builtin_amdgcn_mfma_f32_16x16x32_bf16(ka0, qf[qt][0], z, 0, 0, 0);
            slo = __builtin_amdgcn_mfma_f32_16x16x32_bf16(ka1, qf[qt][1], slo, 0, 0, 0);
            float4v shi = __builtin_amdgcn_mfma_f32_16x16x32_bf16(ka2, qf[qt][0], z, 0, 0, 0);
            shi = __builtin_amdgcn_mfma_f32_16x16x32_bf16(ka3, qf[qt][1], shi, 0, 0, 0);

            const int qabs = q0 + 16 * qt + l15;
            short8v pa;
            float ls = 0.f;
#pragma unroll
            for (int r = 0; r < 4; ++r) {
                const int kvlo = kv0 + 4 * g + r;
                const float plo = (kvlo <= qabs) ? exp2f(slo[r]) : 0.f;
                const float phi = (kvlo + 16 <= qabs) ? exp2f(shi[r]) : 0.f;
                const unsigned short ulo = f2bf(plo);
                const unsigned short uhi = f2bf(phi);
                pa[r]     = (short)ulo;
                pa[4 + r] = (short)uhi;
                ls += bf2f(ulo) + bf2f(uhi);
            }
            lsum[qt] += ls;
#pragma unroll
            for (int f = 0; f < 4; ++f)
                acc[qt][f] = __builtin_amdgcn_mfma_f32_16x16x32_bf16(pa, vb4[f], acc[qt][f], 0, 0, 0);
        }
    }

    // per-wave l reduction across g groups (lanes with same l15 share q row)
#pragma unroll
    for (int qt = 0; qt < 2; ++qt) {
        lsum[qt] += __shfl_xor(lsum[qt], 16);
        lsum[qt] += __shfl_xor(lsum[qt], 32);
    }

#pragma unroll
    for (int qt = 0; qt < 2; ++qt)
#pragma unroll
        for (int f = 0; f < 4; ++f)
#pragma unroll
            for (int r = 0; r < 4; ++r)
                partO[w][16 * qt + 4 * g + r][16 * f + l15] = acc[qt][f][r];
    if (g == 0) {
        partl[w][l15]      = lsum[0];
        partl[w][16 + l15] = lsum[1];
    }
    __syncthreads();

    // combine + normalize: 512 threads, one float4 each (32 rows x 64 cols)
    const int row = threadIdx.x >> 4;          // 0..31
    const int c0  = (threadIdx.x & 15) * 4;
    float lt = 0.f;
#pragma unroll
    for (int ww = 0; ww < 8; ++ww) lt += partl[ww][row];
    const float inv = 1.f / lt;
    float4 o = make_float4(0.f, 0.f, 0.f, 0.f);
#pragma unroll
    for (int ww = 0; ww < 8; ++ww) {
        const float4 s = *(const float4*)&partO[ww][row][c0];
        o.x += s.x; o.y += s.y; o.z += s.z; o.w += s.w;
    }
    o.x *= inv; o.y *= inv; o.z *= inv; o.w *= inv;
    *(float4*)(out + ((size_t)b * T_DIM + q0 + row) * 64 + c0) = o;
}

extern "C" void kernel_launch(void* const* d_in, const int* in_sizes, int n_in,
                              void* d_out, int out_size, void* d_ws, size_t ws_size,
                              hipStream_t stream) {
    const float* x  = (const float*)d_in[0];
    const float* Wq = (const float*)d_in[1];
    const float* bq = (const float*)d_in[2];
    const float* Wk = (const float*)d_in[3];
    const float* bk = (const float*)d_in[4];
    const float* Wv = (const float*)d_in[5];
    const float* bv = (const float*)d_in[6];
    float* out = (float*)d_out;

    const size_t rows = (size_t)B_DIM * T_DIM;            // 16384
    char* ws = (char*)d_ws;
    unsigned short* qb   = (unsigned short*)ws;                       // 2 MB
    unsigned short* kmat = qb + rows * H_DIM;                         // 2 MB
    unsigned short* vP   = kmat + rows * H_DIM;                       // 2 MB
    unsigned short* wt   = vP + rows * H_DIM;                         // 384 KB

    wprep<<<768, 256, 0, stream>>>(Wq, Wk, Wv, wt);
    qkv_gemm<<<256, 512, 0, stream>>>(x, wt, bq, bk, bv, qb, kmat, vP);
    attn_mfma<<<512, 512, 0, stream>>>(qb, kmat, vP, out);
}